// Round 5
// baseline (1137.204 us; speedup 1.0000x reference)
//
#include <hip/hip_runtime.h>

typedef _Float16 f16;
typedef _Float16 f16x8 __attribute__((ext_vector_type(8)));
typedef float f32x16 __attribute__((ext_vector_type(16)));

#define TM 128   // block M tile
#define TN 256   // block N tile
#define BK 64

__device__ __forceinline__ void async_cp16(const void* g, void* l) {
  __builtin_amdgcn_global_load_lds(
      (const __attribute__((address_space(1))) void*)g,
      (__attribute__((address_space(3))) void*)l, 16, 0, 0);
}

// C = A @ Bt^T, A [M][K] f16 row-major, Bt [N][K] f16 row-major.
// Block 128x256, 4 waves of 64x128 (2x4 of 32x32 MFMA accs).
// LDS-byte/MFMA ratio: 144KB per block-iter / 32 MFMA/SIMD -> 46% MfmaUtil
// ceiling (R4's 64x64 waves: 96KB/16 -> 34% ceiling, measured 32.7%).
// LDS k-chunk slot kc holds global chunk kc^(row&7) (R2-verified swizzle).
// NOTE: SQ_LDS_BANK_CONFLICT saturates at 2^24 -- do not trust it.
template <int EPI>
__global__ __launch_bounds__(256) void gemm_f16(
    const f16* __restrict__ A, const f16* __restrict__ Bt,
    const float* __restrict__ bias, f16* __restrict__ C,
    int M, int N, int K) {
  __shared__ alignas(16) f16 sA[TM][BK];
  __shared__ alignas(16) f16 sB[TN][BK];
  const int tid = threadIdx.x;
  const int lane = tid & 63;
  const int wave = tid >> 6;

  // XCD-aware remap: the 4 blocks sharing an A-panel (same mt) get ids
  // spaced 8 apart -> same XCD under round-robin dispatch -> panel stays
  // in that XCD's L2. (R2-verified mechanism: FETCH 530 -> 112 MB.)
  int mt, nt;
  if (gridDim.x == 4 && gridDim.y == 512) {
    const int id = blockIdx.y * 4 + blockIdx.x;
    nt = (id >> 3) & 3;
    mt = (id & 7) * 64 + (id >> 5);
  } else {
    nt = blockIdx.x;
    mt = blockIdx.y;
  }
  const long long bm = (long long)mt * TM;
  const long long bn = (long long)nt * TN;

  const int wm = (wave & 1) * 64;    // wave's 64-row band
  const int wn = (wave >> 1) * 128;  // wave's 128-col band
  const int l31 = lane & 31;
  const int half = lane >> 5;

  // Hoisted per-thread DMA source pointers; advance by BK per K-iter.
  // A: 1024 16B-chunks (4 insts/thread); B: 2048 chunks (8 insts/thread).
  const f16 *aSrc[4], *bSrc[8];
#pragma unroll
  for (int i = 0; i < 4; ++i) {
    const int chunk = wave * 256 + i * 64 + lane;
    const int ml = chunk >> 3;
    const int kc = (chunk & 7) ^ (ml & 7);
    aSrc[i] = A + (bm + ml) * (long long)K + kc * 8;
  }
#pragma unroll
  for (int i = 0; i < 8; ++i) {
    const int chunk = wave * 512 + i * 64 + lane;
    const int ml = chunk >> 3;
    const int kc = (chunk & 7) ^ (ml & 7);
    bSrc[i] = Bt + (bn + ml) * (long long)K + kc * 8;
  }

  f32x16 acc[2][4] = {};  // 2(m) x 4(n) of 32x32 tiles

  const int kIters = K / BK;
  for (int kt = 0; kt < kIters; ++kt) {
#pragma unroll
    for (int i = 0; i < 4; ++i) {
      async_cp16(aSrc[i], &sA[0][0] + (long long)(wave * 256 + i * 64) * 8);
      aSrc[i] += BK;
    }
#pragma unroll
    for (int i = 0; i < 8; ++i) {
      async_cp16(bSrc[i], &sB[0][0] + (long long)(wave * 512 + i * 64) * 8);
      bSrc[i] += BK;
    }
    __syncthreads();

#pragma unroll
    for (int s = 0; s < 4; ++s) {  // K=16 per step
      // A-operand 32x32x16: m = lane&31, k = (lane>>5)*8 + j (B mirrors, n).
      const int csw = ((s * 2 + half) ^ (lane & 7)) * 8;
      f16x8 af[2], bf[4];
#pragma unroll
      for (int i = 0; i < 2; ++i) af[i] = *(const f16x8*)&sA[wm + i * 32 + l31][csw];
#pragma unroll
      for (int j = 0; j < 4; ++j) bf[j] = *(const f16x8*)&sB[wn + j * 32 + l31][csw];
#pragma unroll
      for (int i = 0; i < 2; ++i)
#pragma unroll
        for (int j = 0; j < 4; ++j)
          acc[i][j] = __builtin_amdgcn_mfma_f32_32x32x16_f16(af[i], bf[j],
                                                             acc[i][j], 0, 0, 0);
    }
    __syncthreads();
  }

  // Epilogue. 32x32 C/D: col = lane&31, row = (reg&3) + 8*(reg>>2) + 4*(lane>>5)
  // (m74/m101-verified; R3/R4 confirmed end-to-end).
#pragma unroll
  for (int i = 0; i < 2; ++i)
#pragma unroll
    for (int j = 0; j < 4; ++j) {
      const long long colg = bn + wn + j * 32 + l31;
      float bval = 0.f;
      if (EPI == 0) bval = bias[colg];
#pragma unroll
      for (int reg = 0; reg < 16; ++reg) {
        const long long rowg =
            bm + wm + i * 32 + (reg & 3) + 8 * (reg >> 2) + 4 * half;
        float v = acc[i][j][reg];
        if (EPI == 0) v = fmaxf(v + bval, 0.f);
        C[rowg * N + colg] = (f16)v;
      }
    }
}

// One wave per row: LayerNorm(y) * g + b, relu, write f16. (R2-proven.)
__global__ __launch_bounds__(256) void ln_relu_kernel(
    const f16* __restrict__ Y, const float* __restrict__ g,
    const float* __restrict__ b, f16* __restrict__ H) {
  const int lane = threadIdx.x & 63;
  const int wave = threadIdx.x >> 6;
  const long long row = (long long)blockIdx.x * 4 + wave;
  const f16* y = Y + row * 1024;
  float x[16];
  float s1 = 0.f, s2 = 0.f;
#pragma unroll
  for (int p = 0; p < 2; ++p) {
    f16x8 v = *(const f16x8*)(y + p * 512 + lane * 8);
#pragma unroll
    for (int e = 0; e < 8; ++e) {
      const float f = (float)v[e];
      x[p * 8 + e] = f;
      s1 += f;
      s2 += f * f;
    }
  }
#pragma unroll
  for (int off = 32; off >= 1; off >>= 1) {
    s1 += __shfl_xor(s1, off);
    s2 += __shfl_xor(s2, off);
  }
  const float mean = s1 * (1.f / 1024.f);
  const float var = fmaxf(s2 * (1.f / 1024.f) - mean * mean, 0.f);
  const float inv = rsqrtf(var + 1e-6f);
  f16* h = H + row * 1024;
#pragma unroll
  for (int p = 0; p < 2; ++p) {
    f16x8 o;
#pragma unroll
    for (int e = 0; e < 8; ++e) {
      const int c = p * 512 + lane * 8 + e;
      const float v = (x[p * 8 + e] - mean) * inv * g[c] + b[c];
      o[e] = (f16)fmaxf(v, 0.f);
    }
    *(f16x8*)(h + p * 512 + lane * 8) = o;
  }
}

// Fused layer-3 LN + relu + output dot (R2-proven):
// out[row] = relu(dot(relu(LN(y)*g+b), Wout) + bout)
__global__ __launch_bounds__(256) void ln_relu_out_kernel(
    const f16* __restrict__ Y, const float* __restrict__ g,
    const float* __restrict__ b, const float* __restrict__ Wout,
    const float* __restrict__ bout, float* __restrict__ out) {
  const int lane = threadIdx.x & 63;
  const int wave = threadIdx.x >> 6;
  const long long row = (long long)blockIdx.x * 4 + wave;
  const f16* y = Y + row * 1024;
  float x[16];
  float s1 = 0.f, s2 = 0.f;
#pragma unroll
  for (int p = 0; p < 2; ++p) {
    f16x8 v = *(const f16x8*)(y + p * 512 + lane * 8);
#pragma unroll
    for (int e = 0; e < 8; ++e) {
      const float f = (float)v[e];
      x[p * 8 + e] = f;
      s1 += f;
      s2 += f * f;
    }
  }
#pragma unroll
  for (int off = 32; off >= 1; off >>= 1) {
    s1 += __shfl_xor(s1, off);
    s2 += __shfl_xor(s2, off);
  }
  const float mean = s1 * (1.f / 1024.f);
  const float var = fmaxf(s2 * (1.f / 1024.f) - mean * mean, 0.f);
  const float inv = rsqrtf(var + 1e-6f);
  float dot = 0.f;
#pragma unroll
  for (int p = 0; p < 2; ++p) {
#pragma unroll
    for (int e = 0; e < 8; ++e) {
      const int c = p * 512 + lane * 8 + e;
      const float v = fmaxf((x[p * 8 + e] - mean) * inv * g[c] + b[c], 0.f);
      dot += v * Wout[c];
    }
  }
#pragma unroll
  for (int off = 32; off >= 1; off >>= 1) dot += __shfl_xor(dot, off);
  if (lane == 0) out[row] = fmaxf(dot + bout[0], 0.f);
}

// fp32 -> f16 elementwise (8 per thread)
__global__ __launch_bounds__(256) void cvt_f16_kernel(const float* __restrict__ X,
                                                      f16* __restrict__ Y,
                                                      long long n) {
  const long long i = ((long long)blockIdx.x * 256 + threadIdx.x) * 8;
  if (i >= n) return;
  const float4* X4 = (const float4*)(X + i);
  const float4 a = X4[0], c = X4[1];
  f16x8 o;
  o[0] = (f16)a.x; o[1] = (f16)a.y; o[2] = (f16)a.z; o[3] = (f16)a.w;
  o[4] = (f16)c.x; o[5] = (f16)c.y; o[6] = (f16)c.z; o[7] = (f16)c.w;
  *(f16x8*)(Y + i) = o;
}

// W [K][N] fp32 -> Wt [N][K] f16, 64x64 LDS tiles
__global__ __launch_bounds__(256) void transpose_cvt(const float* __restrict__ W,
                                                     f16* __restrict__ Wt, int K,
                                                     int N) {
  __shared__ float tile[64][65];
  const int bn = blockIdx.x * 64;
  const int bk = blockIdx.y * 64;
  const int tx = threadIdx.x & 63;
  const int ty = threadIdx.x >> 6;  // 0..3
#pragma unroll
  for (int i = 0; i < 64; i += 4)
    tile[ty + i][tx] = W[(long long)(bk + ty + i) * N + bn + tx];
  __syncthreads();
#pragma unroll
  for (int i = 0; i < 64; i += 4)
    Wt[(long long)(bn + ty + i) * K + bk + tx] = (f16)tile[tx][ty + i];
}

extern "C" void kernel_launch(void* const* d_in, const int* in_sizes, int n_in,
                              void* d_out, int out_size, void* d_ws, size_t ws_size,
                              hipStream_t stream) {
  const float* desc = (const float*)d_in[0];
  const float* W0 = (const float*)d_in[1];
  const float* b0 = (const float*)d_in[2];
  const float* W1 = (const float*)d_in[3];
  const float* g1 = (const float*)d_in[4];
  const float* be1 = (const float*)d_in[5];
  const float* W2 = (const float*)d_in[6];
  const float* g2 = (const float*)d_in[7];
  const float* be2 = (const float*)d_in[8];
  const float* W3 = (const float*)d_in[9];
  const float* g3 = (const float*)d_in[10];
  const float* be3 = (const float*)d_in[11];
  const float* Wout = (const float*)d_in[12];
  const float* bout = (const float*)d_in[13];
  float* out = (float*)d_out;

  const long long Nrows = 65536, D = 512, W = 1024;
  char* p = (char*)d_ws;
  f16* descH = (f16*)p; p += Nrows * D * sizeof(f16);   // 67.1 MB
  f16* Wt0 = (f16*)p;   p += D * W * sizeof(f16);       // 1 MB
  f16* Wt1 = (f16*)p;   p += W * W * sizeof(f16);       // 2 MB
  f16* Wt2 = (f16*)p;   p += W * W * sizeof(f16);       // 2 MB
  f16* Wt3 = (f16*)p;   p += W * W * sizeof(f16);       // 2 MB
  f16* H = (f16*)p;     p += Nrows * W * sizeof(f16);   // 134.2 MB
  f16* Y = (f16*)p;     p += Nrows * W * sizeof(f16);   // 134.2 MB
  (void)ws_size; (void)in_sizes; (void)n_in; (void)out_size;

  cvt_f16_kernel<<<(int)(Nrows * D / 8 / 256), 256, 0, stream>>>(desc, descH,
                                                                 Nrows * D);
  transpose_cvt<<<dim3(W / 64, D / 64), 256, 0, stream>>>(W0, Wt0, (int)D, (int)W);
  transpose_cvt<<<dim3(W / 64, W / 64), 256, 0, stream>>>(W1, Wt1, (int)W, (int)W);
  transpose_cvt<<<dim3(W / 64, W / 64), 256, 0, stream>>>(W2, Wt2, (int)W, (int)W);
  transpose_cvt<<<dim3(W / 64, W / 64), 256, 0, stream>>>(W3, Wt3, (int)W, (int)W);

  dim3 ggrid(W / TN, Nrows / TM);  // (4, 512)
  gemm_f16<0><<<ggrid, 256, 0, stream>>>(descH, Wt0, b0, H, (int)Nrows, (int)W, (int)D);

  gemm_f16<1><<<ggrid, 256, 0, stream>>>(H, Wt1, nullptr, Y, (int)Nrows, (int)W, (int)W);
  ln_relu_kernel<<<(int)(Nrows / 4), 256, 0, stream>>>(Y, g1, be1, H);

  gemm_f16<1><<<ggrid, 256, 0, stream>>>(H, Wt2, nullptr, Y, (int)Nrows, (int)W, (int)W);
  ln_relu_kernel<<<(int)(Nrows / 4), 256, 0, stream>>>(Y, g2, be2, H);

  gemm_f16<1><<<ggrid, 256, 0, stream>>>(H, Wt3, nullptr, Y, (int)Nrows, (int)W, (int)W);
  ln_relu_out_kernel<<<(int)(Nrows / 4), 256, 0, stream>>>(Y, g3, be3, Wout, bout, out);
}

// Round 6
// 887.991 us; speedup vs baseline: 1.2806x; 1.2806x over previous
//
#include <hip/hip_runtime.h>

typedef _Float16 f16;
typedef _Float16 f16x8 __attribute__((ext_vector_type(8)));
typedef float f32x16 __attribute__((ext_vector_type(16)));

#define TM 128   // block M tile
#define TN 256   // block N tile
#define BK 64

__device__ __forceinline__ void async_cp16(const void* g, void* l) {
  __builtin_amdgcn_global_load_lds(
      (const __attribute__((address_space(1))) void*)g,
      (__attribute__((address_space(3))) void*)l, 16, 0, 0);
}

// C = A @ Bt^T, A [M][K] f16 row-major, Bt [N][K] f16 row-major.
// Block 128x256, 4 waves of 64x128 (2x4 of 32x32 MFMA accs).
// LDS model (R4-calibrated, ~250 B/cyc effective): 144 KB/block-iter vs
// 258 MFMA-cyc/SIMD -> 46% MfmaUtil ceiling. R5 proved the tile but died
// on registers (140 VGPR + 128 AGPR = 268 > 256 -> 1 block/CU, 24% util).
// Fix: SGPR-base + 32-bit lane offsets for DMA addressing (12 VGPRs, not
// 24) and __launch_bounds__(256,2) to force 2 waves/SIMD = 2 blocks/CU.
// NOTE: SQ_LDS_BANK_CONFLICT saturates at 2^24 -- do not trust it.
template <int EPI>
__global__ __launch_bounds__(256, 2) void gemm_f16(
    const f16* __restrict__ A, const f16* __restrict__ Bt,
    const float* __restrict__ bias, f16* __restrict__ C,
    int M, int N, int K) {
  __shared__ alignas(16) f16 sA[TM][BK];
  __shared__ alignas(16) f16 sB[TN][BK];
  const int tid = threadIdx.x;
  const int lane = tid & 63;
  const int wave = tid >> 6;

  // XCD-aware remap: the 4 blocks sharing an A-panel (same mt) get ids
  // spaced 8 apart -> same XCD under round-robin dispatch -> panel stays
  // in that XCD's L2. (R2-verified mechanism: FETCH 530 -> 112 MB.)
  int mt, nt;
  if (gridDim.x == 4 && gridDim.y == 512) {
    const int id = blockIdx.y * 4 + blockIdx.x;
    nt = (id >> 3) & 3;
    mt = (id & 7) * 64 + (id >> 5);
  } else {
    nt = blockIdx.x;
    mt = blockIdx.y;
  }
  const long long bm = (long long)mt * TM;
  const long long bn = (long long)nt * TN;

  const int wm = (wave & 1) * 64;    // wave's 64-row band
  const int wn = (wave >> 1) * 128;  // wave's 128-col band
  const int l31 = lane & 31;
  const int half = lane >> 5;

  // Block-uniform bases (SGPR) + 32-bit lane-dependent element offsets
  // (1 VGPR each instead of a 64-bit pointer pair).
  const f16* const Abase = A + bm * (long long)K;
  const f16* const Bbase = Bt + bn * (long long)K;
  int aOff[4], bOff[8];
#pragma unroll
  for (int i = 0; i < 4; ++i) {
    const int chunk = wave * 256 + i * 64 + lane;
    const int ml = chunk >> 3;
    const int kc = (chunk & 7) ^ (ml & 7);  // R2-verified XOR swizzle
    aOff[i] = ml * K + kc * 8;
  }
#pragma unroll
  for (int i = 0; i < 8; ++i) {
    const int chunk = wave * 512 + i * 64 + lane;
    const int ml = chunk >> 3;
    const int kc = (chunk & 7) ^ (ml & 7);
    bOff[i] = ml * K + kc * 8;
  }

  f32x16 acc[2][4] = {};  // 2(m) x 4(n) of 32x32 tiles

  const int kIters = K / BK;
  for (int kt = 0; kt < kIters; ++kt) {
    const int k0 = kt * BK;
#pragma unroll
    for (int i = 0; i < 4; ++i)
      async_cp16(Abase + aOff[i] + k0,
                 &sA[0][0] + (wave * 256 + i * 64) * 8);
#pragma unroll
    for (int i = 0; i < 8; ++i)
      async_cp16(Bbase + bOff[i] + k0,
                 &sB[0][0] + (wave * 512 + i * 64) * 8);
    __syncthreads();

#pragma unroll
    for (int s = 0; s < 4; ++s) {  // K=16 per step
      // A-operand 32x32x16: m = lane&31, k = (lane>>5)*8 + j (B mirrors, n).
      const int csw = ((s * 2 + half) ^ (lane & 7)) * 8;
      f16x8 af[2], bf[4];
#pragma unroll
      for (int i = 0; i < 2; ++i) af[i] = *(const f16x8*)&sA[wm + i * 32 + l31][csw];
#pragma unroll
      for (int j = 0; j < 4; ++j) bf[j] = *(const f16x8*)&sB[wn + j * 32 + l31][csw];
#pragma unroll
      for (int i = 0; i < 2; ++i)
#pragma unroll
        for (int j = 0; j < 4; ++j)
          acc[i][j] = __builtin_amdgcn_mfma_f32_32x32x16_f16(af[i], bf[j],
                                                             acc[i][j], 0, 0, 0);
    }
    __syncthreads();
  }

  // Epilogue. 32x32 C/D: col = lane&31, row = (reg&3) + 8*(reg>>2) + 4*(lane>>5)
  // (m74/m101-verified; R3/R4/R5 confirmed end-to-end).
#pragma unroll
  for (int i = 0; i < 2; ++i)
#pragma unroll
    for (int j = 0; j < 4; ++j) {
      const long long colg = bn + wn + j * 32 + l31;
      float bval = 0.f;
      if (EPI == 0) bval = bias[colg];
#pragma unroll
      for (int reg = 0; reg < 16; ++reg) {
        const long long rowg =
            bm + wm + i * 32 + (reg & 3) + 8 * (reg >> 2) + 4 * half;
        float v = acc[i][j][reg];
        if (EPI == 0) v = fmaxf(v + bval, 0.f);
        C[rowg * N + colg] = (f16)v;
      }
    }
}

// One wave per row: LayerNorm(y) * g + b, relu, write f16. (R2-proven.)
__global__ __launch_bounds__(256) void ln_relu_kernel(
    const f16* __restrict__ Y, const float* __restrict__ g,
    const float* __restrict__ b, f16* __restrict__ H) {
  const int lane = threadIdx.x & 63;
  const int wave = threadIdx.x >> 6;
  const long long row = (long long)blockIdx.x * 4 + wave;
  const f16* y = Y + row * 1024;
  float x[16];
  float s1 = 0.f, s2 = 0.f;
#pragma unroll
  for (int p = 0; p < 2; ++p) {
    f16x8 v = *(const f16x8*)(y + p * 512 + lane * 8);
#pragma unroll
    for (int e = 0; e < 8; ++e) {
      const float f = (float)v[e];
      x[p * 8 + e] = f;
      s1 += f;
      s2 += f * f;
    }
  }
#pragma unroll
  for (int off = 32; off >= 1; off >>= 1) {
    s1 += __shfl_xor(s1, off);
    s2 += __shfl_xor(s2, off);
  }
  const float mean = s1 * (1.f / 1024.f);
  const float var = fmaxf(s2 * (1.f / 1024.f) - mean * mean, 0.f);
  const float inv = rsqrtf(var + 1e-6f);
  f16* h = H + row * 1024;
#pragma unroll
  for (int p = 0; p < 2; ++p) {
    f16x8 o;
#pragma unroll
    for (int e = 0; e < 8; ++e) {
      const int c = p * 512 + lane * 8 + e;
      const float v = (x[p * 8 + e] - mean) * inv * g[c] + b[c];
      o[e] = (f16)fmaxf(v, 0.f);
    }
    *(f16x8*)(h + p * 512 + lane * 8) = o;
  }
}

// Fused layer-3 LN + relu + output dot (R2-proven):
// out[row] = relu(dot(relu(LN(y)*g+b), Wout) + bout)
__global__ __launch_bounds__(256) void ln_relu_out_kernel(
    const f16* __restrict__ Y, const float* __restrict__ g,
    const float* __restrict__ b, const float* __restrict__ Wout,
    const float* __restrict__ bout, float* __restrict__ out) {
  const int lane = threadIdx.x & 63;
  const int wave = threadIdx.x >> 6;
  const long long row = (long long)blockIdx.x * 4 + wave;
  const f16* y = Y + row * 1024;
  float x[16];
  float s1 = 0.f, s2 = 0.f;
#pragma unroll
  for (int p = 0; p < 2; ++p) {
    f16x8 v = *(const f16x8*)(y + p * 512 + lane * 8);
#pragma unroll
    for (int e = 0; e < 8; ++e) {
      const float f = (float)v[e];
      x[p * 8 + e] = f;
      s1 += f;
      s2 += f * f;
    }
  }
#pragma unroll
  for (int off = 32; off >= 1; off >>= 1) {
    s1 += __shfl_xor(s1, off);
    s2 += __shfl_xor(s2, off);
  }
  const float mean = s1 * (1.f / 1024.f);
  const float var = fmaxf(s2 * (1.f / 1024.f) - mean * mean, 0.f);
  const float inv = rsqrtf(var + 1e-6f);
  float dot = 0.f;
#pragma unroll
  for (int p = 0; p < 2; ++p) {
#pragma unroll
    for (int e = 0; e < 8; ++e) {
      const int c = p * 512 + lane * 8 + e;
      const float v = fmaxf((x[p * 8 + e] - mean) * inv * g[c] + b[c], 0.f);
      dot += v * Wout[c];
    }
  }
#pragma unroll
  for (int off = 32; off >= 1; off >>= 1) dot += __shfl_xor(dot, off);
  if (lane == 0) out[row] = fmaxf(dot + bout[0], 0.f);
}

// fp32 -> f16 elementwise (8 per thread)
__global__ __launch_bounds__(256) void cvt_f16_kernel(const float* __restrict__ X,
                                                      f16* __restrict__ Y,
                                                      long long n) {
  const long long i = ((long long)blockIdx.x * 256 + threadIdx.x) * 8;
  if (i >= n) return;
  const float4* X4 = (const float4*)(X + i);
  const float4 a = X4[0], c = X4[1];
  f16x8 o;
  o[0] = (f16)a.x; o[1] = (f16)a.y; o[2] = (f16)a.z; o[3] = (f16)a.w;
  o[4] = (f16)c.x; o[5] = (f16)c.y; o[6] = (f16)c.z; o[7] = (f16)c.w;
  *(f16x8*)(Y + i) = o;
}

// W [K][N] fp32 -> Wt [N][K] f16, 64x64 LDS tiles
__global__ __launch_bounds__(256) void transpose_cvt(const float* __restrict__ W,
                                                     f16* __restrict__ Wt, int K,
                                                     int N) {
  __shared__ float tile[64][65];
  const int bn = blockIdx.x * 64;
  const int bk = blockIdx.y * 64;
  const int tx = threadIdx.x & 63;
  const int ty = threadIdx.x >> 6;  // 0..3
#pragma unroll
  for (int i = 0; i < 64; i += 4)
    tile[ty + i][tx] = W[(long long)(bk + ty + i) * N + bn + tx];
  __syncthreads();
#pragma unroll
  for (int i = 0; i < 64; i += 4)
    Wt[(long long)(bn + ty + i) * K + bk + tx] = (f16)tile[tx][ty + i];
}

extern "C" void kernel_launch(void* const* d_in, const int* in_sizes, int n_in,
                              void* d_out, int out_size, void* d_ws, size_t ws_size,
                              hipStream_t stream) {
  const float* desc = (const float*)d_in[0];
  const float* W0 = (const float*)d_in[1];
  const float* b0 = (const float*)d_in[2];
  const float* W1 = (const float*)d_in[3];
  const float* g1 = (const float*)d_in[4];
  const float* be1 = (const float*)d_in[5];
  const float* W2 = (const float*)d_in[6];
  const float* g2 = (const float*)d_in[7];
  const float* be2 = (const float*)d_in[8];
  const float* W3 = (const float*)d_in[9];
  const float* g3 = (const float*)d_in[10];
  const float* be3 = (const float*)d_in[11];
  const float* Wout = (const float*)d_in[12];
  const float* bout = (const float*)d_in[13];
  float* out = (float*)d_out;

  const long long Nrows = 65536, D = 512, W = 1024;
  char* p = (char*)d_ws;
  f16* descH = (f16*)p; p += Nrows * D * sizeof(f16);   // 67.1 MB
  f16* Wt0 = (f16*)p;   p += D * W * sizeof(f16);       // 1 MB
  f16* Wt1 = (f16*)p;   p += W * W * sizeof(f16);       // 2 MB
  f16* Wt2 = (f16*)p;   p += W * W * sizeof(f16);       // 2 MB
  f16* Wt3 = (f16*)p;   p += W * W * sizeof(f16);       // 2 MB
  f16* H = (f16*)p;     p += Nrows * W * sizeof(f16);   // 134.2 MB
  f16* Y = (f16*)p;     p += Nrows * W * sizeof(f16);   // 134.2 MB
  (void)ws_size; (void)in_sizes; (void)n_in; (void)out_size;

  cvt_f16_kernel<<<(int)(Nrows * D / 8 / 256), 256, 0, stream>>>(desc, descH,
                                                                 Nrows * D);
  transpose_cvt<<<dim3(W / 64, D / 64), 256, 0, stream>>>(W0, Wt0, (int)D, (int)W);
  transpose_cvt<<<dim3(W / 64, W / 64), 256, 0, stream>>>(W1, Wt1, (int)W, (int)W);
  transpose_cvt<<<dim3(W / 64, W / 64), 256, 0, stream>>>(W2, Wt2, (int)W, (int)W);
  transpose_cvt<<<dim3(W / 64, W / 64), 256, 0, stream>>>(W3, Wt3, (int)W, (int)W);

  dim3 ggrid(W / TN, Nrows / TM);  // (4, 512)
  gemm_f16<0><<<ggrid, 256, 0, stream>>>(descH, Wt0, b0, H, (int)Nrows, (int)W, (int)D);

  gemm_f16<1><<<ggrid, 256, 0, stream>>>(H, Wt1, nullptr, Y, (int)Nrows, (int)W, (int)W);
  ln_relu_kernel<<<(int)(Nrows / 4), 256, 0, stream>>>(Y, g1, be1, H);

  gemm_f16<1><<<ggrid, 256, 0, stream>>>(H, Wt2, nullptr, Y, (int)Nrows, (int)W, (int)W);
  ln_relu_kernel<<<(int)(Nrows / 4), 256, 0, stream>>>(Y, g2, be2, H);

  gemm_f16<1><<<ggrid, 256, 0, stream>>>(H, Wt3, nullptr, Y, (int)Nrows, (int)W, (int)W);
  ln_relu_out_kernel<<<(int)(Nrows / 4), 256, 0, stream>>>(Y, g3, be3, Wout, bout, out);
}